// Round 13
// baseline (2823.489 us; speedup 1.0000x reference)
//
#include <hip/hip_runtime.h>
#include <hip/hip_fp16.h>

typedef _Float16 half_t;
typedef __attribute__((ext_vector_type(8))) _Float16 f16x8;
typedef __attribute__((ext_vector_type(4))) float f32x4;

#define DIM   3072
#define NH    24
#define DH    128
#define MLP_D 12288
#define LSEQ  4096
#define BATCH 2
#define NROWS 8192           // B*L
#define N1    21504          // 3*DIM + MLP
#define QKV_N 9216           // 3*DIM
#define CAT_N 15360          // DIM + MLP

__device__ __forceinline__ void gload16(const void* g, void* l) {
  __builtin_amdgcn_global_load_lds((const __attribute__((address_space(1))) void*)g,
                                   (__attribute__((address_space(3))) void*)l, 16, 0, 0);
}

__device__ __forceinline__ float gelu_tanh(float x) {
  float u = 0.7978845608028654f * (x + 0.044715f * x * x * x);
  float t = 1.f - 2.f / (__expf(2.f * u) + 1.f);   // tanh(u)
  return 0.5f * x * (1.f + t);
}

struct EpiParams {
  const float* bias;
  float* outF; int ldoF;
  half_t* o1; int ldo1;   // qkv dest (EPI0) / S dest fp16 (EPI1)
  half_t* o2; int ldo2;   // concat dest (EPI0 gelu part, EPI2)
  const float* resid;
  const float* gate;      // emb+6144, stride 9216 per batch
  float scale;
};

// ============================================================================
// R13: counted-vmcnt prefetch x 4 waves/SIMD — the untested cell.
// 128(M) x 256(N) tile, BK=32, 8 waves (2M x 4N, 64x64 each).
// 3-deep LDS ring (3 x 24 KiB = 72 KiB) => 2 blocks/CU (4 waves/SIMD) AND
// counted vmcnt(3): stage tile t+2 during tile t; gate drains t+1 only
// (t+2 stays in flight across the barrier -> HBM latency covered by a full
// tile of compute). Per tile: 16 MFMA cluster -> stage -> vmcnt(3) -> barrier
// -> read next tile's 8 frags (LDS latency hidden by the other 3 waves/SIMD).
// LDS slot: A [128r][32k] @0 (8KB), B [256r][32k] @8192 (16KB).
// 16B-chunk XOR swizzle phys = logical ^ ((row>>1)&3), inverse perm applied
// on the GLOBAL source, LDS dest linear (rule #21; verified 0 conflicts).
// ============================================================================
template<int EPI>
__global__ __launch_bounds__(512, 4) void gemm128(
    const half_t* __restrict__ A, int lda,
    const half_t* __restrict__ B, int ldb,
    int nbx, int nby, int nsplit, int K, EpiParams ep)
{
  __shared__ __align__(16) char lds[73728];
  const int t = threadIdx.x, lane = t & 63, wid = t >> 6;

  // ---- block swizzle: XCD-contiguous chunks + 8-M-block supertile ----
  const int nwg = nbx * nby;
  const int wg = blockIdx.x;
  const int id = (wg & 7) * (nwg >> 3) + (wg >> 3);   // bijective (nwg%8==0)
  const int panel = 8 * nbx;
  const int bm = (id / panel) * 8 + (id % 8);
  const int bn = (id % panel) / 8;
  const int brow = bm * 128, bcol = bn * 256;
  const int wr = wid >> 2, wc = wid & 3;              // 2 x 4 waves, 64x64

  f32x4 acc[4][4];
#pragma unroll
  for (int m = 0; m < 4; ++m)
#pragma unroll
    for (int n = 0; n < 4; ++n) acc[m][n] = (f32x4){0.f, 0.f, 0.f, 0.f};

  // ---- staging: lane l -> row (l>>2), chunk (l&3); global source chunk
  // inverse-permuted: src = (l&3) ^ ((row>>1)&3) = (l&3) ^ ((l>>3)&3)
  const int scol = (((lane & 3) ^ ((lane >> 3) & 3)) * 8);   // elements
  const half_t* pA = A + (size_t)(brow + wid * 16 + (lane >> 2)) * lda + scol;
  const half_t* pB = B + (size_t)(bcol + wid * 32 + (lane >> 2)) * ldb + scol;
  const int NT = K >> 5;

  // ---- fragment read offsets: row = lane&15, chunk_log = lane>>4,
  // phys = chunk_log ^ ((row>>1)&3) ----
  const int pc = (((lane >> 4) ^ ((lane >> 1) & 3)) << 4);   // bytes
  const int arow  = (wr * 64 + (lane & 15)) * 64 + pc;          // + mi*1024
  const int brow_o = 8192 + (wc * 64 + (lane & 15)) * 64 + pc;  // + nj*1024

  f16x8 af[4], bf[4];

#define STAGE(tk, slot) {                                                   \
    char* sb = lds + (slot) * 24576;                                        \
    const half_t* ga = pA + (size_t)(tk) * 32;                              \
    const half_t* gb = pB + (size_t)(tk) * 32;                              \
    gload16(ga, sb + wid * 1024);                                           \
    gload16(gb, sb + 8192 + wid * 2048);                                    \
    gload16(gb + (size_t)16 * ldb, sb + 8192 + wid * 2048 + 1024); }

#define READF(slot) {                                                       \
    char* cb = lds + (slot) * 24576;                                        \
    af[0] = *(const f16x8*)(cb + arow);                                     \
    af[1] = *(const f16x8*)(cb + arow + 1024);                              \
    af[2] = *(const f16x8*)(cb + arow + 2048);                              \
    af[3] = *(const f16x8*)(cb + arow + 3072);                              \
    bf[0] = *(const f16x8*)(cb + brow_o);                                   \
    bf[1] = *(const f16x8*)(cb + brow_o + 1024);                            \
    bf[2] = *(const f16x8*)(cb + brow_o + 2048);                            \
    bf[3] = *(const f16x8*)(cb + brow_o + 3072); }

  // ---- prologue: stage tiles 0,1; drain tile 0; read its frags ----
  STAGE(0, 0) STAGE(1, 1)
  asm volatile("s_waitcnt vmcnt(3)" ::: "memory");   // tile 0 landed
  __builtin_amdgcn_s_barrier();
  __builtin_amdgcn_sched_barrier(0);
  READF(0)

  int s0 = 0, s1 = 1, s2 = 2;    // cur / next / landing ring slots
  for (int tt = 0; tt < NT; ++tt) {
    // 16 MFMA on frags read last iteration (compiler inserts lgkm wait)
    __builtin_amdgcn_s_setprio(1);
#pragma unroll
    for (int mi = 0; mi < 4; ++mi)
#pragma unroll
      for (int nj = 0; nj < 4; ++nj)
        acc[mi][nj] = __builtin_amdgcn_mfma_f32_16x16x32_f16(
            af[mi], bf[nj], acc[mi][nj], 0, 0, 0);
    __builtin_amdgcn_s_setprio(0);

    if (tt + 2 < NT) STAGE(tt + 2, s2)

    if (tt + 2 < NT)      asm volatile("s_waitcnt vmcnt(3)" ::: "memory");
    else if (tt + 1 < NT) asm volatile("s_waitcnt vmcnt(0)" ::: "memory");
    __builtin_amdgcn_s_barrier();          // all waves' t+1 DMA visible
    __builtin_amdgcn_sched_barrier(0);     // keep following reads below

    if (tt + 1 < NT) READF(s1)

    int tmp = s0; s0 = s1; s1 = s2; s2 = tmp;
  }
#undef STAGE
#undef READF

  // ---- epilogue ----
  const int laneR = lane & 15;
  const int colb = bcol + wc * 64;
  const int rowb = brow + wr * 64 + (lane >> 4) * 4;
#pragma unroll
  for (int mi = 0; mi < 4; ++mi) {
#pragma unroll
    for (int nj = 0; nj < 4; ++nj) {
      int col = colb + nj * 16 + laneR;
#pragma unroll
      for (int j = 0; j < 4; ++j) {
        int row = rowb + mi * 16 + j;
        float v = acc[mi][nj][j];
        if (EPI == 0) {
          v += ep.bias[col];
          if (col < nsplit) {
            ep.o1[(size_t)row * ep.ldo1 + col] = (half_t)v;
          } else {
            ep.o2[(size_t)row * ep.ldo2 + DIM + (col - nsplit)] = (half_t)gelu_tanh(v);
          }
        } else if (EPI == 1) {
          ep.o1[(size_t)row * ep.ldo1 + col] = (half_t)(v * ep.scale);
        } else if (EPI == 2) {
          ep.o2[(size_t)row * ep.ldo2 + col] = (half_t)v;
        } else {
          v += ep.bias[col];
          int b = row >> 12;
          float g = ep.gate[(size_t)b * QKV_N + col];
          float r = ep.resid[(size_t)row * DIM + col];
          ep.outF[(size_t)row * ep.ldoF + col] = r + g * v;
        }
      }
    }
  }
}

// emb = silu(temb) @ w_lin + b_lin   (2 x 9216)
__global__ __launch_bounds__(256) void k_emb(
    const float* __restrict__ temb, const float* __restrict__ w_lin,
    const float* __restrict__ b_lin, float* __restrict__ emb)
{
  __shared__ float s[DIM];
  int b = blockIdx.y;
  int col = blockIdx.x * 256 + threadIdx.x;
  const float* tr = temb + (size_t)b * DIM;
  for (int k = threadIdx.x; k < DIM; k += 256) {
    float x = tr[k];
    s[k] = x / (1.f + __expf(-x));
  }
  __syncthreads();
  float acc = b_lin[col];
  for (int k = 0; k < DIM; k += 4) {
    acc += s[k] * w_lin[(size_t)k * QKV_N + col]
         + s[k + 1] * w_lin[(size_t)(k + 1) * QKV_N + col]
         + s[k + 2] * w_lin[(size_t)(k + 2) * QKV_N + col]
         + s[k + 3] * w_lin[(size_t)(k + 3) * QKV_N + col];
  }
  emb[(size_t)b * QKV_N + col] = acc;
}

// LayerNorm + (1+scale)*xhat + shift -> fp16
__global__ __launch_bounds__(256) void k_lnmod(
    const float* __restrict__ hs, const float* __restrict__ emb,
    half_t* __restrict__ xmod)
{
  int row = blockIdx.x;
  int b = row >> 12;
  const float* x = hs + (size_t)row * DIM;
  int t = threadIdx.x;
  float s = 0.f, s2 = 0.f;
  float4 v[3];
#pragma unroll
  for (int i = 0; i < 3; ++i) {
    v[i] = ((const float4*)x)[t + 256 * i];
    s  += v[i].x + v[i].y + v[i].z + v[i].w;
    s2 += v[i].x * v[i].x + v[i].y * v[i].y + v[i].z * v[i].z + v[i].w * v[i].w;
  }
  for (int o = 32; o; o >>= 1) { s += __shfl_xor(s, o); s2 += __shfl_xor(s2, o); }
  __shared__ float rs[4], rs2[4];
  int lane = t & 63, w = t >> 6;
  if (lane == 0) { rs[w] = s; rs2[w] = s2; }
  __syncthreads();
  s = rs[0] + rs[1] + rs[2] + rs[3];
  s2 = rs2[0] + rs2[1] + rs2[2] + rs2[3];
  float mu = s * (1.f / DIM);
  float var = s2 * (1.f / DIM) - mu * mu;
  float rstd = rsqrtf(var + 1e-6f);
  const float* shift = emb + (size_t)b * QKV_N;
  const float* scale = shift + DIM;
#pragma unroll
  for (int i = 0; i < 3; ++i) {
    int g = t + 256 * i;
    float4 sc = ((const float4*)scale)[g];
    float4 sh = ((const float4*)shift)[g];
    half_t ob[4];
    float vv[4] = {v[i].x, v[i].y, v[i].z, v[i].w};
    float scv[4] = {sc.x, sc.y, sc.z, sc.w};
    float shv[4] = {sh.x, sh.y, sh.z, sh.w};
#pragma unroll
    for (int j = 0; j < 4; ++j) {
      float xn = (vv[j] - mu) * rstd;
      ob[j] = (half_t)(xn * (1.f + scv[j]) + shv[j]);
    }
    *(uint2*)&xmod[(size_t)row * DIM + g * 4] = *(uint2*)ob;
  }
}

// f32 (RxC) -> fp16 transposed (CxR)
__global__ __launch_bounds__(256) void k_transpose_cvt(
    const float* __restrict__ in, half_t* __restrict__ out, int R, int C)
{
  __shared__ float s[64][65];
  int c0 = blockIdx.x * 64, r0 = blockIdx.y * 64;
  int tx = threadIdx.x & 63, ty = threadIdx.x >> 6;
#pragma unroll
  for (int j = 0; j < 16; ++j) {
    int r = ty + j * 4;
    s[r][tx] = in[(size_t)(r0 + r) * C + c0 + tx];
  }
  __syncthreads();
#pragma unroll
  for (int j = 0; j < 16; ++j) {
    int c = ty + j * 4;
    out[(size_t)(c0 + c) * R + r0 + tx] = (half_t)s[tx][c];
  }
}

// RMS + RoPE on q,k in-place in qkv buffer. One wave per (row, head, q/k).
__global__ __launch_bounds__(256) void k_qk_rmsrope(
    half_t* __restrict__ qkv, const float* __restrict__ rope,
    const float* __restrict__ q_scale, const float* __restrict__ k_scale)
{
  int w = blockIdx.x * 4 + (threadIdx.x >> 6);
  int lane = threadIdx.x & 63;
  int qk = w & 1;
  int hr = w >> 1;               // bl*24 + h
  int h = hr % 24;
  int bl = hr / 24;              // b*4096 + l
  size_t base = (size_t)bl * QKV_N + qk * DIM + h * DH;
  float x0 = (float)qkv[base + lane * 2];
  float x1 = (float)qkv[base + lane * 2 + 1];
  float ss = x0 * x0 + x1 * x1;
  for (int o = 32; o; o >>= 1) ss += __shfl_xor(ss, o);
  float r = rsqrtf(ss * (1.f / DH) + 1e-6f);
  const float* sc = qk ? k_scale : q_scale;
  float xs0 = x0 * r * sc[lane * 2];
  float xs1 = x1 * r * sc[lane * 2 + 1];
  int l = bl & (LSEQ - 1);
  float4 fr = ((const float4*)rope)[(size_t)l * 64 + lane];
  qkv[base + lane * 2]     = (half_t)(fr.x * xs0 + fr.y * xs1);
  qkv[base + lane * 2 + 1] = (half_t)(fr.z * xs0 + fr.w * xs1);
}

// v part of qkv -> vT (per batch: DIM x LSEQ), tiled transpose
__global__ __launch_bounds__(256) void k_vT(
    const half_t* __restrict__ qkv, half_t* __restrict__ vT)
{
  __shared__ half_t s[64][65];
  int b = blockIdx.z;
  int l0 = blockIdx.x * 64, d0 = blockIdx.y * 64;
  int tx = threadIdx.x & 63, ty = threadIdx.x >> 6;
#pragma unroll
  for (int j = 0; j < 16; ++j) {
    int l = ty + j * 4;
    s[l][tx] = qkv[(size_t)(b * LSEQ + l0 + l) * QKV_N + 2 * DIM + d0 + tx];
  }
  __syncthreads();
#pragma unroll
  for (int j = 0; j < 16; ++j) {
    int d = ty + j * 4;
    vT[((size_t)b * DIM + d0 + d) * LSEQ + l0 + tx] = s[tx][d];
  }
}

// row softmax: S (4096 fp16) -> P fp16
__global__ __launch_bounds__(256) void k_softmax(
    const half_t* __restrict__ S, half_t* __restrict__ P)
{
  int row = blockIdx.x;
  const half_t* srow = S + (size_t)row * LSEQ;
  int t = threadIdx.x;
  f16x8 hv[2];
  float vf[16];
  float mx = -1e30f;
#pragma unroll
  for (int i = 0; i < 2; ++i) {
    hv[i] = ((const f16x8*)srow)[t + 256 * i];
#pragma unroll
    for (int j = 0; j < 8; ++j) {
      vf[i * 8 + j] = (float)hv[i][j];
      mx = fmaxf(mx, vf[i * 8 + j]);
    }
  }
  for (int o = 32; o; o >>= 1) mx = fmaxf(mx, __shfl_xor(mx, o));
  __shared__ float rmx[4], rsum[4];
  int lane = t & 63, w = t >> 6;
  if (lane == 0) rmx[w] = mx;
  __syncthreads();
  mx = fmaxf(fmaxf(rmx[0], rmx[1]), fmaxf(rmx[2], rmx[3]));
  float s = 0.f;
#pragma unroll
  for (int i = 0; i < 16; ++i) {
    vf[i] = __expf(vf[i] - mx);
    s += vf[i];
  }
  for (int o = 32; o; o >>= 1) s += __shfl_xor(s, o);
  if (lane == 0) rsum[w] = s;
  __syncthreads();
  s = rsum[0] + rsum[1] + rsum[2] + rsum[3];
  float inv = 1.f / s;
#pragma unroll
  for (int i = 0; i < 2; ++i) {
    f16x8 ob;
#pragma unroll
    for (int j = 0; j < 8; ++j) ob[j] = (half_t)(vf[i * 8 + j] * inv);
    ((f16x8*)&P[(size_t)row * LSEQ])[t + 256 * i] = ob;
  }
}

extern "C" void kernel_launch(void* const* d_in, const int* in_sizes, int n_in,
                              void* d_out, int out_size, void* d_ws, size_t ws_size,
                              hipStream_t stream) {
  const float* hs      = (const float*)d_in[0];
  const float* temb    = (const float*)d_in[1];
  const float* rope    = (const float*)d_in[2];
  const float* w_lin   = (const float*)d_in[3];
  const float* b_lin   = (const float*)d_in[4];
  const float* w1      = (const float*)d_in[5];
  const float* b1      = (const float*)d_in[6];
  const float* w2      = (const float*)d_in[7];
  const float* b2      = (const float*)d_in[8];
  const float* q_scale = (const float*)d_in[9];
  const float* k_scale = (const float*)d_in[10];
  float* out = (float*)d_out;

  char* ws = (char*)d_ws;
  size_t off = 0;
  auto alloc = [&](size_t bytes) { char* p = ws + off; off += (bytes + 255) & ~(size_t)255; return p; };
  float*  emb    = (float*) alloc((size_t)BATCH * QKV_N * 4);
  half_t* xmod   = (half_t*)alloc((size_t)NROWS * DIM * 2);
  half_t* w1T    = (half_t*)alloc((size_t)N1 * DIM * 2);
  half_t* w2T    = (half_t*)alloc((size_t)DIM * CAT_N * 2);
  half_t* qkv    = (half_t*)alloc((size_t)NROWS * QKV_N * 2);
  half_t* concat = (half_t*)alloc((size_t)NROWS * CAT_N * 2);
  half_t* vT     = (half_t*)alloc((size_t)BATCH * DIM * LSEQ * 2);
  half_t* Sbuf   = (half_t*)alloc((size_t)LSEQ * LSEQ * 2);
  half_t* Pbuf   = (half_t*)alloc((size_t)LSEQ * LSEQ * 2);
  (void)ws_size; (void)n_in; (void)in_sizes; (void)out_size;

  k_emb<<<dim3(QKV_N / 256, BATCH), 256, 0, stream>>>(temb, w_lin, b_lin, emb);
  k_transpose_cvt<<<dim3(N1 / 64, DIM / 64), 256, 0, stream>>>(w1, w1T, DIM, N1);
  k_transpose_cvt<<<dim3(DIM / 64, CAT_N / 64), 256, 0, stream>>>(w2, w2T, CAT_N, DIM);
  k_lnmod<<<NROWS, 256, 0, stream>>>(hs, emb, xmod);

  // GEMM1: proj = xmod @ w1 + b1 ; qkv part -> qkv buf, mlp part -> gelu -> concat[:,3072:]
  EpiParams ep1 = {b1, nullptr, 0, qkv, QKV_N, concat, CAT_N, nullptr, nullptr, 0.f};
  gemm128<0><<<(N1 / 256) * (NROWS / 128), 512, 0, stream>>>(
      xmod, DIM, w1T, DIM, N1 / 256, NROWS / 128, QKV_N, DIM, ep1);

  k_qk_rmsrope<<<(NROWS * NH * 2) / 4, 256, 0, stream>>>(qkv, rope, q_scale, k_scale);
  k_vT<<<dim3(LSEQ / 64, DIM / 64, BATCH), 256, 0, stream>>>(qkv, vT);

  for (int b = 0; b < BATCH; ++b) {
    const half_t* qb = qkv + (size_t)b * LSEQ * QKV_N;
    EpiParams epS = {nullptr, nullptr, 0, Sbuf, LSEQ, nullptr, 0, nullptr, nullptr, 0.08838834764831845f};
    gemm128<1><<<(LSEQ / 256) * (LSEQ / 128), 512, 0, stream>>>(
        qb, QKV_N, qb + DIM, QKV_N, LSEQ / 256, LSEQ / 128, 0, DIM, epS);
    k_softmax<<<LSEQ, 256, 0, stream>>>(Sbuf, Pbuf);
    EpiParams epPV = {nullptr, nullptr, 0, nullptr, 0,
                      concat + (size_t)b * LSEQ * CAT_N, CAT_N, nullptr, nullptr, 0.f};
    gemm128<2><<<(DIM / 256) * (LSEQ / 128), 512, 0, stream>>>(
        Pbuf, LSEQ, vT + (size_t)b * DIM * LSEQ, LSEQ, DIM / 256, LSEQ / 128, 0, LSEQ, epPV);
  }

  // GEMM2: out = resid + gate * (concat @ w2 + b2)
  EpiParams ep2 = {b2, out, DIM, nullptr, 0, nullptr, 0, hs, emb + 2 * DIM, 0.f};
  gemm128<3><<<(DIM / 256) * (NROWS / 128), 512, 0, stream>>>(
      concat, CAT_N, w2T, CAT_N, DIM / 256, NROWS / 128, 0, CAT_N, ep2);
}

// Round 14
// 2779.333 us; speedup vs baseline: 1.0159x; 1.0159x over previous
//
#include <hip/hip_runtime.h>
#include <hip/hip_fp16.h>

typedef _Float16 half_t;
typedef __attribute__((ext_vector_type(8))) _Float16 f16x8;
typedef __attribute__((ext_vector_type(4))) float f32x4;

#define DIM   3072
#define NH    24
#define DH    128
#define MLP_D 12288
#define LSEQ  4096
#define BATCH 2
#define NROWS 8192           // B*L
#define N1    21504          // 3*DIM + MLP
#define QKV_N 9216           // 3*DIM
#define CAT_N 15360          // DIM + MLP

__device__ __forceinline__ void gload16(const void* g, void* l) {
  __builtin_amdgcn_global_load_lds((const __attribute__((address_space(1))) void*)g,
                                   (__attribute__((address_space(3))) void*)l, 16, 0, 0);
}

__device__ __forceinline__ float gelu_tanh(float x) {
  float u = 0.7978845608028654f * (x + 0.044715f * x * x * x);
  float t = 1.f - 2.f / (__expf(2.f * u) + 1.f);   // tanh(u)
  return 0.5f * x * (1.f + t);
}

struct EpiParams {
  const float* bias;
  float* outF; int ldoF;
  half_t* o1; int ldo1;   // qkv dest (EPI0) / S dest fp16 (EPI1)
  half_t* o2; int ldo2;   // concat dest (EPI0 gelu part, EPI2)
  const float* resid;
  const float* gate;      // emb+6144, stride 9216 per batch
  float scale;
};

// ============================================================================
// R12 structure (best measured: 2788us total, gemm<0> 1150us, 0 conflicts),
// extended with batching: grid = nper * nbatch blocks; bz = id / nper selects
// the batch; A/B get element strides strA/strB; EPI1/EPI2 dests get strO.
// 256x256 tile, BK=64, 8 waves (2M x 4N), 2-deep LDS dbuf, counted vmcnt(6),
// unpinned compiler scheduling, setprio around MFMA clusters. XOR chunk
// swizzle phys = logical ^ ((row>>1)&3), inverse perm on GLOBAL source.
// ============================================================================
template<int EPI>
__global__ __launch_bounds__(512, 2) void gemm256(
    const half_t* __restrict__ A, int lda,
    const half_t* __restrict__ B, int ldb,
    int nbx, int nper, size_t strA, size_t strB, size_t strO,
    int nsplit, int K, EpiParams ep)
{
  __shared__ __align__(16) char lds[131072];
  const int t = threadIdx.x, lane = t & 63, wid = t >> 6;

  // ---- block swizzle: XCD-contiguous chunks + 8-M-block supertile ----
  const int nwg = gridDim.x;
  const int wg = blockIdx.x;
  const int id = (wg & 7) * (nwg >> 3) + (wg >> 3);   // bijective (nwg%8==0)
  const int bz = id / nper;
  const int rid = id - bz * nper;
  const int panel = 8 * nbx;
  const int bm = (rid / panel) * 8 + (rid % 8);
  const int bn = (rid % panel) / 8;
  const int brow = bm * 256, bcol = bn * 256;
  const int wr = wid >> 2, wc = wid & 3;              // 2 x 4 waves
  A += bz * strA;
  B += bz * strB;

  f32x4 acc[8][4];
#pragma unroll
  for (int m = 0; m < 8; ++m)
#pragma unroll
    for (int n = 0; n < 4; ++n) acc[m][n] = (f32x4){0.f, 0.f, 0.f, 0.f};

  // ---- staging pointers: lane l -> row (l>>2)[+16], chunk (l&3); source
  // chunk inverse-permuted so LDS holds phys = logical ^ ((row>>1)&3)
  const int scol = (((lane & 3) ^ ((lane >> 3) & 3)) * 8);   // halves
  const half_t* pA = A + (size_t)(brow + wid * 32 + (lane >> 2)) * lda + scol;
  const half_t* pB = B + (size_t)(bcol + wid * 32 + (lane >> 2)) * ldb + scol;
  const int wrow = wid * 2048;          // byte offset of this wave's 32 rows
  const int NT = K >> 6;

  // ---- fragment read offsets (swizzled chunk) ----
  const int pc = (((lane >> 4) ^ ((lane >> 1) & 3)) << 4);   // bytes
  const int aoff = (wr * 128 + (lane & 15)) * 64 + pc;
  const int boff = 32768 + (wc * 64 + (lane & 15)) * 64 + pc;

  f16x8 af[2][4], bf[2][4];

#define STAGE_A(bb, kh, tk) {                                               \
    gload16(pA + (size_t)(tk) * 64 + (kh) * 32,                             \
            (bb) + (kh) * 16384 + wrow);                                    \
    gload16(pA + (size_t)(tk) * 64 + (kh) * 32 + (size_t)16 * lda,          \
            (bb) + (kh) * 16384 + wrow + 1024); }
#define STAGE_B(bb, kh, tk) {                                               \
    gload16(pB + (size_t)(tk) * 64 + (kh) * 32,                             \
            (bb) + 32768 + (kh) * 16384 + wrow);                            \
    gload16(pB + (size_t)(tk) * 64 + (kh) * 32 + (size_t)16 * ldb,          \
            (bb) + 32768 + (kh) * 16384 + wrow + 1024); }

#define MFMA_Q(accoff, ab, bb2)                                             \
    _Pragma("unroll")                                                       \
    for (int mi = 0; mi < 4; ++mi)                                          \
      _Pragma("unroll")                                                     \
      for (int nj = 0; nj < 4; ++nj)                                        \
        acc[(accoff) + mi][nj] = __builtin_amdgcn_mfma_f32_16x16x32_f16(    \
            af[ab][mi], bf[bb2][nj], acc[(accoff) + mi][nj], 0, 0, 0);

  // ---- prologue: stage tiles 0 and 1; pre-read Q0 fragments of tile 0 ----
  {
    char* b0 = lds;
    char* b1 = lds + 65536;
    STAGE_B(b0, 0, 0); STAGE_A(b0, 0, 0); STAGE_B(b0, 1, 0); STAGE_A(b0, 1, 0);
    STAGE_B(b1, 0, 1); STAGE_A(b1, 0, 1); STAGE_B(b1, 1, 1); STAGE_A(b1, 1, 1);
    asm volatile("s_waitcnt vmcnt(8)" ::: "memory");   // tile 0 landed
    __builtin_amdgcn_s_barrier();
#pragma unroll
    for (int mi = 0; mi < 4; ++mi) af[0][mi] = *(const f16x8*)(lds + aoff + mi * 1024);
#pragma unroll
    for (int nj = 0; nj < 4; ++nj) bf[0][nj] = *(const f16x8*)(lds + boff + nj * 1024);
    __builtin_amdgcn_s_barrier();      // all waves issued pre-reads
  }

  for (int tt = 0; tt < NT; ++tt) {
    char* cb = lds + (size_t)(tt & 1) * 65536;
    char* nb = lds + (size_t)((tt & 1) ^ 1) * 65536;

    // ===== P0: MFMA Q0 (kk0,mh0); read af[1] <- A kh0 mh1; stage B kh0 =====
    __builtin_amdgcn_s_setprio(1);
    MFMA_Q(0, 0, 0)
    __builtin_amdgcn_s_setprio(0);
#pragma unroll
    for (int mi = 0; mi < 4; ++mi) af[1][mi] = *(const f16x8*)(cb + aoff + 4096 + mi * 1024);
    if (tt + 2 < NT) STAGE_B(cb, 0, tt + 2);
    __builtin_amdgcn_s_barrier();

    // ===== P1: MFMA Q1 (kk0,mh1) w/ bf0; read af[0] <- A kh1 mh0, bf[1] <- B kh1;
    //           stage A kh0 =====
    __builtin_amdgcn_s_setprio(1);
    MFMA_Q(4, 1, 0)
    __builtin_amdgcn_s_setprio(0);
#pragma unroll
    for (int mi = 0; mi < 4; ++mi) af[0][mi] = *(const f16x8*)(cb + aoff + 16384 + mi * 1024);
#pragma unroll
    for (int nj = 0; nj < 4; ++nj) bf[1][nj] = *(const f16x8*)(cb + boff + 16384 + nj * 1024);
    if (tt + 2 < NT) STAGE_A(cb, 0, tt + 2);
    __builtin_amdgcn_s_barrier();

    // ===== P2: MFMA Q2 (kk1,mh0) w/ bf1; read af[1] <- A kh1 mh1; stage B kh1;
    //           vmcnt gate for next-buffer reads =====
    __builtin_amdgcn_s_setprio(1);
    MFMA_Q(0, 0, 1)
    __builtin_amdgcn_s_setprio(0);
#pragma unroll
    for (int mi = 0; mi < 4; ++mi) af[1][mi] = *(const f16x8*)(cb + aoff + 16384 + 4096 + mi * 1024);
    if (tt + 2 < NT) STAGE_B(cb, 1, tt + 2);
    if (tt + 2 < NT) asm volatile("s_waitcnt vmcnt(6)" ::: "memory");
    else             asm volatile("s_waitcnt vmcnt(0)" ::: "memory");
    __builtin_amdgcn_s_barrier();

    // ===== P3: MFMA Q3 (kk1,mh1) w/ bf1; read next tile's Q0 frags from nb;
    //           stage A kh1 =====
    __builtin_amdgcn_s_setprio(1);
    MFMA_Q(4, 1, 1)
    __builtin_amdgcn_s_setprio(0);
    if (tt + 1 < NT) {
#pragma unroll
      for (int mi = 0; mi < 4; ++mi) af[0][mi] = *(const f16x8*)(nb + aoff + mi * 1024);
#pragma unroll
      for (int nj = 0; nj < 4; ++nj) bf[0][nj] = *(const f16x8*)(nb + boff + nj * 1024);
    }
    if (tt + 2 < NT) STAGE_A(cb, 1, tt + 2);
    __builtin_amdgcn_s_barrier();
  }
#undef STAGE_A
#undef STAGE_B
#undef MFMA_Q

  // ---- epilogue ----
  half_t* o1 = ep.o1;
  half_t* o2 = ep.o2;
  if (EPI == 1) o1 += (size_t)bz * strO;
  if (EPI == 2) o2 += (size_t)bz * strO;
  const int laneR = lane & 15;
  const int colb = bcol + wc * 64;
  const int rowb = brow + wr * 128 + (lane >> 4) * 4;
#pragma unroll
  for (int mi = 0; mi < 8; ++mi) {
#pragma unroll
    for (int nj = 0; nj < 4; ++nj) {
      int col = colb + nj * 16 + laneR;
#pragma unroll
      for (int j = 0; j < 4; ++j) {
        int row = rowb + mi * 16 + j;
        float v = acc[mi][nj][j];
        if (EPI == 0) {
          v += ep.bias[col];
          if (col < nsplit) {
            o1[(size_t)row * ep.ldo1 + col] = (half_t)v;
          } else {
            o2[(size_t)row * ep.ldo2 + DIM + (col - nsplit)] = (half_t)gelu_tanh(v);
          }
        } else if (EPI == 1) {
          o1[(size_t)row * ep.ldo1 + col] = (half_t)(v * ep.scale);
        } else if (EPI == 2) {
          o2[(size_t)row * ep.ldo2 + col] = (half_t)v;
        } else {
          v += ep.bias[col];
          int b = row >> 12;
          float g = ep.gate[(size_t)b * QKV_N + col];
          float r = ep.resid[(size_t)row * DIM + col];
          ep.outF[(size_t)row * ep.ldoF + col] = r + g * v;
        }
      }
    }
  }
}

// ---- vectorized 64x64 f32->fp16 transpose tile ----
__device__ __forceinline__ void tp_tile(
    const float* __restrict__ in, half_t* __restrict__ out, int R, int C,
    int r0, int c0, float (*s)[65], int t)
{
  const int tx = t & 15, ty = t >> 4;   // 16 x 16
#pragma unroll
  for (int j = 0; j < 4; ++j) {
    int r = ty + j * 16;
    float4 v = *(const float4*)&in[(size_t)(r0 + r) * C + c0 + tx * 4];
    s[r][tx * 4 + 0] = v.x; s[r][tx * 4 + 1] = v.y;
    s[r][tx * 4 + 2] = v.z; s[r][tx * 4 + 3] = v.w;
  }
  __syncthreads();
#pragma unroll
  for (int j = 0; j < 4; ++j) {
    int c = ty + j * 16;
    half_t o[4] = {(half_t)s[tx * 4 + 0][c], (half_t)s[tx * 4 + 1][c],
                   (half_t)s[tx * 4 + 2][c], (half_t)s[tx * 4 + 3][c]};
    *(uint2*)&out[(size_t)(c0 + c) * R + r0 + tx * 4] = *(uint2*)o;
  }
}

#define NBW1 ((N1 / 64) * (DIM / 64))      // 16128
#define NBW2 ((DIM / 64) * (CAT_N / 64))   // 11520
#define NBEMB ((QKV_N / 256) * BATCH)      // 72

// fused pre-pass: transpose w1, transpose w2, emb = silu(temb)@w_lin+b_lin
__global__ __launch_bounds__(256) void k_pre(
    const float* __restrict__ w1, half_t* __restrict__ w1T,
    const float* __restrict__ w2, half_t* __restrict__ w2T,
    const float* __restrict__ temb, const float* __restrict__ w_lin,
    const float* __restrict__ b_lin, float* __restrict__ emb)
{
  __shared__ float s[64][65];
  int id = blockIdx.x;
  if (id < NBW1) {
    int cx = id % (N1 / 64), ry = id / (N1 / 64);
    tp_tile(w1, w1T, DIM, N1, ry * 64, cx * 64, s, threadIdx.x);
    return;
  }
  id -= NBW1;
  if (id < NBW2) {
    int cx = id % (DIM / 64), ry = id / (DIM / 64);
    tp_tile(w2, w2T, CAT_N, DIM, ry * 64, cx * 64, s, threadIdx.x);
    return;
  }
  id -= NBW2;
  {
    float* sf = &s[0][0];
    int b = id / (QKV_N / 256);
    int col = (id % (QKV_N / 256)) * 256 + threadIdx.x;
    const float* tr = temb + (size_t)b * DIM;
    for (int k = threadIdx.x; k < DIM; k += 256) {
      float x = tr[k];
      sf[k] = x / (1.f + __expf(-x));
    }
    __syncthreads();
    float acc = b_lin[col];
    for (int k = 0; k < DIM; k += 4) {
      acc += sf[k] * w_lin[(size_t)k * QKV_N + col]
           + sf[k + 1] * w_lin[(size_t)(k + 1) * QKV_N + col]
           + sf[k + 2] * w_lin[(size_t)(k + 2) * QKV_N + col]
           + sf[k + 3] * w_lin[(size_t)(k + 3) * QKV_N + col];
    }
    emb[(size_t)b * QKV_N + col] = acc;
  }
}

// LayerNorm + (1+scale)*xhat + shift -> fp16
__global__ __launch_bounds__(256) void k_lnmod(
    const float* __restrict__ hs, const float* __restrict__ emb,
    half_t* __restrict__ xmod)
{
  int row = blockIdx.x;
  int b = row >> 12;
  const float* x = hs + (size_t)row * DIM;
  int t = threadIdx.x;
  float s = 0.f, s2 = 0.f;
  float4 v[3];
#pragma unroll
  for (int i = 0; i < 3; ++i) {
    v[i] = ((const float4*)x)[t + 256 * i];
    s  += v[i].x + v[i].y + v[i].z + v[i].w;
    s2 += v[i].x * v[i].x + v[i].y * v[i].y + v[i].z * v[i].z + v[i].w * v[i].w;
  }
  for (int o = 32; o; o >>= 1) { s += __shfl_xor(s, o); s2 += __shfl_xor(s2, o); }
  __shared__ float rs[4], rs2[4];
  int lane = t & 63, w = t >> 6;
  if (lane == 0) { rs[w] = s; rs2[w] = s2; }
  __syncthreads();
  s = rs[0] + rs[1] + rs[2] + rs[3];
  s2 = rs2[0] + rs2[1] + rs2[2] + rs2[3];
  float mu = s * (1.f / DIM);
  float var = s2 * (1.f / DIM) - mu * mu;
  float rstd = rsqrtf(var + 1e-6f);
  const float* shift = emb + (size_t)b * QKV_N;
  const float* scale = shift + DIM;
#pragma unroll
  for (int i = 0; i < 3; ++i) {
    int g = t + 256 * i;
    float4 sc = ((const float4*)scale)[g];
    float4 sh = ((const float4*)shift)[g];
    half_t ob[4];
    float vv[4] = {v[i].x, v[i].y, v[i].z, v[i].w};
    float scv[4] = {sc.x, sc.y, sc.z, sc.w};
    float shv[4] = {sh.x, sh.y, sh.z, sh.w};
#pragma unroll
    for (int j = 0; j < 4; ++j) {
      float xn = (vv[j] - mu) * rstd;
      ob[j] = (half_t)(xn * (1.f + scv[j]) + shv[j]);
    }
    *(uint2*)&xmod[(size_t)row * DIM + g * 4] = *(uint2*)ob;
  }
}

#define NROPE ((NROWS * NH * 2) / 4)                   // 98304
#define NVT   ((LSEQ / 64) * (DIM / 64) * BATCH)       // 6144

// fused: RMS+RoPE on q,k (in-place) AND v -> vT transpose
__global__ __launch_bounds__(256) void k_ropevt(
    half_t* __restrict__ qkv, const float* __restrict__ rope,
    const float* __restrict__ q_scale, const float* __restrict__ k_scale,
    half_t* __restrict__ vT)
{
  __shared__ half_t s[64][65];
  int id = blockIdx.x;
  if (id < NROPE) {
    int w = id * 4 + (threadIdx.x >> 6);
    int lane = threadIdx.x & 63;
    int qk = w & 1;
    int hr = w >> 1;               // bl*24 + h
    int h = hr % 24;
    int bl = hr / 24;              // b*4096 + l
    size_t base = (size_t)bl * QKV_N + qk * DIM + h * DH;
    float x0 = (float)qkv[base + lane * 2];
    float x1 = (float)qkv[base + lane * 2 + 1];
    float ss = x0 * x0 + x1 * x1;
    for (int o = 32; o; o >>= 1) ss += __shfl_xor(ss, o);
    float r = rsqrtf(ss * (1.f / DH) + 1e-6f);
    const float* sc = qk ? k_scale : q_scale;
    float xs0 = x0 * r * sc[lane * 2];
    float xs1 = x1 * r * sc[lane * 2 + 1];
    int l = bl & (LSEQ - 1);
    float4 fr = ((const float4*)rope)[(size_t)l * 64 + lane];
    qkv[base + lane * 2]     = (half_t)(fr.x * xs0 + fr.y * xs1);
    qkv[base + lane * 2 + 1] = (half_t)(fr.z * xs0 + fr.w * xs1);
    return;
  }
  id -= NROPE;
  {
    int nb = (LSEQ / 64) * (DIM / 64);
    int b = id / nb;
    int rem = id % nb;
    int l0 = (rem % (LSEQ / 64)) * 64, d0 = (rem / (LSEQ / 64)) * 64;
    int tx = threadIdx.x & 63, ty = threadIdx.x >> 6;
#pragma unroll
    for (int j = 0; j < 16; ++j) {
      int l = ty + j * 4;
      s[l][tx] = qkv[(size_t)(b * LSEQ + l0 + l) * QKV_N + 2 * DIM + d0 + tx];
    }
    __syncthreads();
#pragma unroll
    for (int j = 0; j < 16; ++j) {
      int d = ty + j * 4;
      vT[((size_t)b * DIM + d0 + d) * LSEQ + l0 + tx] = s[tx][d];
    }
  }
}

// row softmax: S (4096 fp16) -> P fp16; grid = BATCH*LSEQ
__global__ __launch_bounds__(256) void k_softmax(
    const half_t* __restrict__ S, half_t* __restrict__ P)
{
  int row = blockIdx.x;
  const half_t* srow = S + (size_t)row * LSEQ;
  int t = threadIdx.x;
  f16x8 hv[2];
  float vf[16];
  float mx = -1e30f;
#pragma unroll
  for (int i = 0; i < 2; ++i) {
    hv[i] = ((const f16x8*)srow)[t + 256 * i];
#pragma unroll
    for (int j = 0; j < 8; ++j) {
      vf[i * 8 + j] = (float)hv[i][j];
      mx = fmaxf(mx, vf[i * 8 + j]);
    }
  }
  for (int o = 32; o; o >>= 1) mx = fmaxf(mx, __shfl_xor(mx, o));
  __shared__ float rmx[4], rsum[4];
  int lane = t & 63, w = t >> 6;
  if (lane == 0) rmx[w] = mx;
  __syncthreads();
  mx = fmaxf(fmaxf(rmx[0], rmx[1]), fmaxf(rmx[2], rmx[3]));
  float s = 0.f;
#pragma unroll
  for (int i = 0; i < 16; ++i) {
    vf[i] = __expf(vf[i] - mx);
    s += vf[i];
  }
  for (int o = 32; o; o >>= 1) s += __shfl_xor(s, o);
  if (lane == 0) rsum[w] = s;
  __syncthreads();
  s = rsum[0] + rsum[1] + rsum[2] + rsum[3];
  float inv = 1.f / s;
#pragma unroll
  for (int i = 0; i < 2; ++i) {
    f16x8 ob;
#pragma unroll
    for (int j = 0; j < 8; ++j) ob[j] = (half_t)(vf[i * 8 + j] * inv);
    ((f16x8*)&P[(size_t)row * LSEQ])[t + 256 * i] = ob;
  }
}

extern "C" void kernel_launch(void* const* d_in, const int* in_sizes, int n_in,
                              void* d_out, int out_size, void* d_ws, size_t ws_size,
                              hipStream_t stream) {
  const float* hs      = (const float*)d_in[0];
  const float* temb    = (const float*)d_in[1];
  const float* rope    = (const float*)d_in[2];
  const float* w_lin   = (const float*)d_in[3];
  const float* b_lin   = (const float*)d_in[4];
  const float* w1      = (const float*)d_in[5];
  const float* b1      = (const float*)d_in[6];
  const float* w2      = (const float*)d_in[7];
  const float* b2      = (const float*)d_in[8];
  const float* q_scale = (const float*)d_in[9];
  const float* k_scale = (const float*)d_in[10];
  float* out = (float*)d_out;

  char* ws = (char*)d_ws;
  size_t off = 0;
  auto alloc = [&](size_t bytes) { char* p = ws + off; off += (bytes + 255) & ~(size_t)255; return p; };
  float*  emb    = (float*) alloc((size_t)BATCH * QKV_N * 4);
  half_t* xmod   = (half_t*)alloc((size_t)NROWS * DIM * 2);
  half_t* w1T    = (half_t*)alloc((size_t)N1 * DIM * 2);
  half_t* w2T    = (half_t*)alloc((size_t)DIM * CAT_N * 2);
  half_t* qkv    = (half_t*)alloc((size_t)NROWS * QKV_N * 2);
  half_t* concat = (half_t*)alloc((size_t)NROWS * CAT_N * 2);
  half_t* vT     = (half_t*)alloc((size_t)BATCH * DIM * LSEQ * 2);
  half_t* Sbuf   = (half_t*)alloc((size_t)BATCH * LSEQ * LSEQ * 2);
  half_t* Pbuf   = (half_t*)alloc((size_t)BATCH * LSEQ * LSEQ * 2);
  (void)ws_size; (void)n_in; (void)in_sizes; (void)out_size;

  // fused pre-pass: both weight transposes + emb
  k_pre<<<NBW1 + NBW2 + NBEMB, 256, 0, stream>>>(w1, w1T, w2, w2T, temb, w_lin, b_lin, emb);
  k_lnmod<<<NROWS, 256, 0, stream>>>(hs, emb, xmod);

  // GEMM1: proj = xmod @ w1 + b1 ; qkv part -> qkv buf, mlp part -> gelu -> concat[:,3072:]
  EpiParams ep1 = {b1, nullptr, 0, qkv, QKV_N, concat, CAT_N, nullptr, nullptr, 0.f};
  gemm256<0><<<(N1 / 256) * (NROWS / 256), 512, 0, stream>>>(
      xmod, DIM, w1T, DIM, N1 / 256, (N1 / 256) * (NROWS / 256), 0, 0, 0, QKV_N, DIM, ep1);

  // fused RMS+RoPE (q,k) + vT transpose
  k_ropevt<<<NROPE + NVT, 256, 0, stream>>>(qkv, rope, q_scale, k_scale, vT);

  // batched attention: S = q @ k^T (both batches, one launch)
  EpiParams epS = {nullptr, nullptr, 0, Sbuf, LSEQ, nullptr, 0, nullptr, nullptr, 0.08838834764831845f};
  gemm256<1><<<(LSEQ / 256) * (LSEQ / 256) * BATCH, 512, 0, stream>>>(
      qkv, QKV_N, qkv + DIM, QKV_N,
      LSEQ / 256, (LSEQ / 256) * (LSEQ / 256),
      (size_t)LSEQ * QKV_N, (size_t)LSEQ * QKV_N, (size_t)LSEQ * LSEQ,
      0, DIM, epS);
  k_softmax<<<BATCH * LSEQ, 256, 0, stream>>>(Sbuf, Pbuf);
  // batched PV: attn_out = P @ vT^T -> concat[:, :DIM]
  EpiParams epPV = {nullptr, nullptr, 0, nullptr, 0, concat, CAT_N, nullptr, nullptr, 0.f};
  gemm256<2><<<(DIM / 256) * (LSEQ / 256) * BATCH, 512, 0, stream>>>(
      Pbuf, LSEQ, vT, LSEQ,
      DIM / 256, (DIM / 256) * (LSEQ / 256),
      (size_t)LSEQ * LSEQ, (size_t)DIM * LSEQ, (size_t)LSEQ * CAT_N,
      0, LSEQ, epPV);

  // GEMM2: out = resid + gate * (concat @ w2 + b2)
  EpiParams ep2 = {b2, out, DIM, nullptr, 0, nullptr, 0, hs, emb + 2 * DIM, 0.f};
  gemm256<3><<<(DIM / 256) * (NROWS / 256), 512, 0, stream>>>(
      concat, CAT_N, w2T, CAT_N, DIM / 256, (DIM / 256) * (NROWS / 256), 0, 0, 0, 0, CAT_N, ep2);
}

// Round 15
// 2620.961 us; speedup vs baseline: 1.0773x; 1.0604x over previous
//
#include <hip/hip_runtime.h>
#include <hip/hip_fp16.h>

typedef _Float16 half_t;
typedef __attribute__((ext_vector_type(8))) _Float16 f16x8;
typedef __attribute__((ext_vector_type(4))) float f32x4;

#define DIM   3072
#define NH    24
#define DH    128
#define MLP_D 12288
#define LSEQ  4096
#define BATCH 2
#define NROWS 8192           // B*L
#define N1    21504          // 3*DIM + MLP
#define QKV_N 9216           // 3*DIM
#define CAT_N 15360          // DIM + MLP

__device__ __forceinline__ void gload16(const void* g, void* l) {
  __builtin_amdgcn_global_load_lds((const __attribute__((address_space(1))) void*)g,
                                   (__attribute__((address_space(3))) void*)l, 16, 0, 0);
}

__device__ __forceinline__ float gelu_tanh(float x) {
  float u = 0.7978845608028654f * (x + 0.044715f * x * x * x);
  float t = 1.f - 2.f / (__expf(2.f * u) + 1.f);   // tanh(u)
  return 0.5f * x * (1.f + t);
}

struct EpiParams {
  const float* bias;
  float* outF; int ldoF;
  half_t* o1; int ldo1;   // qkv dest (EPI0) / S dest fp16 (EPI1)
  half_t* o2; int ldo2;   // concat dest (EPI0 gelu part) / generic fp16 (EPI2)
  const float* resid;
  const float* gate;      // emb+6144, stride 9216 per batch
  float scale;
};

// ============================================================================
// R12 GEMM structure (best measured; 0 conflicts), batched/sliced: grid =
// nper * nslice; bz = id / nper selects batch OR K-slice; A/B shifted by
// bz*strA / bz*strB elements; EPI1/EPI2 dest shifted by bz*strO.
// Split-K via bz: strA/strB = column offset into K, K = slice length.
// 256x256 tile, BK=64, 8 waves, 2-deep LDS dbuf, counted vmcnt(6), unpinned
// compiler scheduling, setprio on MFMA clusters. XOR chunk swizzle
// phys = logical ^ ((row>>1)&3), inverse perm on GLOBAL source.
// ============================================================================
template<int EPI>
__global__ __launch_bounds__(512, 2) void gemm256(
    const half_t* __restrict__ A, int lda,
    const half_t* __restrict__ B, int ldb,
    int nbx, int nper, size_t strA, size_t strB, size_t strO,
    int nsplit, int K, EpiParams ep)
{
  __shared__ __align__(16) char lds[131072];
  const int t = threadIdx.x, lane = t & 63, wid = t >> 6;

  // ---- block swizzle: XCD-contiguous chunks + 8-M-block supertile ----
  const int nwg = gridDim.x;
  const int wg = blockIdx.x;
  const int id = (wg & 7) * (nwg >> 3) + (wg >> 3);   // bijective (nwg%8==0)
  const int bz = id / nper;
  const int rid = id - bz * nper;
  const int panel = 8 * nbx;
  const int bm = (rid / panel) * 8 + (rid % 8);
  const int bn = (rid % panel) / 8;
  const int brow = bm * 256, bcol = bn * 256;
  const int wr = wid >> 2, wc = wid & 3;              // 2 x 4 waves
  A += bz * strA;
  B += bz * strB;

  f32x4 acc[8][4];
#pragma unroll
  for (int m = 0; m < 8; ++m)
#pragma unroll
    for (int n = 0; n < 4; ++n) acc[m][n] = (f32x4){0.f, 0.f, 0.f, 0.f};

  // ---- staging pointers: lane l -> row (l>>2)[+16], chunk (l&3); source
  // chunk inverse-permuted so LDS holds phys = logical ^ ((row>>1)&3)
  const int scol = (((lane & 3) ^ ((lane >> 3) & 3)) * 8);   // halves
  const half_t* pA = A + (size_t)(brow + wid * 32 + (lane >> 2)) * lda + scol;
  const half_t* pB = B + (size_t)(bcol + wid * 32 + (lane >> 2)) * ldb + scol;
  const int wrow = wid * 2048;          // byte offset of this wave's 32 rows
  const int NT = K >> 6;

  // ---- fragment read offsets (swizzled chunk) ----
  const int pc = (((lane >> 4) ^ ((lane >> 1) & 3)) << 4);   // bytes
  const int aoff = (wr * 128 + (lane & 15)) * 64 + pc;
  const int boff = 32768 + (wc * 64 + (lane & 15)) * 64 + pc;

  f16x8 af[2][4], bf[2][4];

#define STAGE_A(bb, kh, tk) {                                               \
    gload16(pA + (size_t)(tk) * 64 + (kh) * 32,                             \
            (bb) + (kh) * 16384 + wrow);                                    \
    gload16(pA + (size_t)(tk) * 64 + (kh) * 32 + (size_t)16 * lda,          \
            (bb) + (kh) * 16384 + wrow + 1024); }
#define STAGE_B(bb, kh, tk) {                                               \
    gload16(pB + (size_t)(tk) * 64 + (kh) * 32,                             \
            (bb) + 32768 + (kh) * 16384 + wrow);                            \
    gload16(pB + (size_t)(tk) * 64 + (kh) * 32 + (size_t)16 * ldb,          \
            (bb) + 32768 + (kh) * 16384 + wrow + 1024); }

#define MFMA_Q(accoff, ab, bb2)                                             \
    _Pragma("unroll")                                                       \
    for (int mi = 0; mi < 4; ++mi)                                          \
      _Pragma("unroll")                                                     \
      for (int nj = 0; nj < 4; ++nj)                                        \
        acc[(accoff) + mi][nj] = __builtin_amdgcn_mfma_f32_16x16x32_f16(    \
            af[ab][mi], bf[bb2][nj], acc[(accoff) + mi][nj], 0, 0, 0);

  // ---- prologue: stage tiles 0 and 1; pre-read Q0 fragments of tile 0 ----
  {
    char* b0 = lds;
    char* b1 = lds + 65536;
    STAGE_B(b0, 0, 0); STAGE_A(b0, 0, 0); STAGE_B(b0, 1, 0); STAGE_A(b0, 1, 0);
    STAGE_B(b1, 0, 1); STAGE_A(b1, 0, 1); STAGE_B(b1, 1, 1); STAGE_A(b1, 1, 1);
    asm volatile("s_waitcnt vmcnt(8)" ::: "memory");   // tile 0 landed
    __builtin_amdgcn_s_barrier();
#pragma unroll
    for (int mi = 0; mi < 4; ++mi) af[0][mi] = *(const f16x8*)(lds + aoff + mi * 1024);
#pragma unroll
    for (int nj = 0; nj < 4; ++nj) bf[0][nj] = *(const f16x8*)(lds + boff + nj * 1024);
    __builtin_amdgcn_s_barrier();      // all waves issued pre-reads
  }

  for (int tt = 0; tt < NT; ++tt) {
    char* cb = lds + (size_t)(tt & 1) * 65536;
    char* nb = lds + (size_t)((tt & 1) ^ 1) * 65536;

    // ===== P0: MFMA Q0 (kk0,mh0); read af[1] <- A kh0 mh1; stage B kh0 =====
    __builtin_amdgcn_s_setprio(1);
    MFMA_Q(0, 0, 0)
    __builtin_amdgcn_s_setprio(0);
#pragma unroll
    for (int mi = 0; mi < 4; ++mi) af[1][mi] = *(const f16x8*)(cb + aoff + 4096 + mi * 1024);
    if (tt + 2 < NT) STAGE_B(cb, 0, tt + 2);
    __builtin_amdgcn_s_barrier();

    // ===== P1: MFMA Q1 (kk0,mh1) w/ bf0; read af[0] <- A kh1 mh0, bf[1] <- B kh1;
    //           stage A kh0 =====
    __builtin_amdgcn_s_setprio(1);
    MFMA_Q(4, 1, 0)
    __builtin_amdgcn_s_setprio(0);
#pragma unroll
    for (int mi = 0; mi < 4; ++mi) af[0][mi] = *(const f16x8*)(cb + aoff + 16384 + mi * 1024);
#pragma unroll
    for (int nj = 0; nj < 4; ++nj) bf[1][nj] = *(const f16x8*)(cb + boff + 16384 + nj * 1024);
    if (tt + 2 < NT) STAGE_A(cb, 0, tt + 2);
    __builtin_amdgcn_s_barrier();

    // ===== P2: MFMA Q2 (kk1,mh0) w/ bf1; read af[1] <- A kh1 mh1; stage B kh1;
    //           vmcnt gate for next-buffer reads =====
    __builtin_amdgcn_s_setprio(1);
    MFMA_Q(0, 0, 1)
    __builtin_amdgcn_s_setprio(0);
#pragma unroll
    for (int mi = 0; mi < 4; ++mi) af[1][mi] = *(const f16x8*)(cb + aoff + 16384 + 4096 + mi * 1024);
    if (tt + 2 < NT) STAGE_B(cb, 1, tt + 2);
    if (tt + 2 < NT) asm volatile("s_waitcnt vmcnt(6)" ::: "memory");
    else             asm volatile("s_waitcnt vmcnt(0)" ::: "memory");
    __builtin_amdgcn_s_barrier();

    // ===== P3: MFMA Q3 (kk1,mh1) w/ bf1; read next tile's Q0 frags from nb;
    //           stage A kh1 =====
    __builtin_amdgcn_s_setprio(1);
    MFMA_Q(4, 1, 1)
    __builtin_amdgcn_s_setprio(0);
    if (tt + 1 < NT) {
#pragma unroll
      for (int mi = 0; mi < 4; ++mi) af[0][mi] = *(const f16x8*)(nb + aoff + mi * 1024);
#pragma unroll
      for (int nj = 0; nj < 4; ++nj) bf[0][nj] = *(const f16x8*)(nb + boff + nj * 1024);
    }
    if (tt + 2 < NT) STAGE_A(cb, 1, tt + 2);
    __builtin_amdgcn_s_barrier();
  }
#undef STAGE_A
#undef STAGE_B
#undef MFMA_Q

  // ---- epilogue ----
  half_t* o1 = ep.o1;
  half_t* o2 = ep.o2;
  if (EPI == 1) o1 += (size_t)bz * strO;
  if (EPI == 2) o2 += (size_t)bz * strO;
  const int laneR = lane & 15;
  const int colb = bcol + wc * 64;
  const int rowb = brow + wr * 128 + (lane >> 4) * 4;
#pragma unroll
  for (int mi = 0; mi < 8; ++mi) {
#pragma unroll
    for (int nj = 0; nj < 4; ++nj) {
      int col = colb + nj * 16 + laneR;
#pragma unroll
      for (int j = 0; j < 4; ++j) {
        int row = rowb + mi * 16 + j;
        float v = acc[mi][nj][j];
        if (EPI == 0) {
          v += ep.bias[col];
          if (col < nsplit) {
            o1[(size_t)row * ep.ldo1 + col] = (half_t)v;
          } else {
            o2[(size_t)row * ep.ldo2 + DIM + (col - nsplit)] = (half_t)gelu_tanh(v);
          }
        } else if (EPI == 1) {
          o1[(size_t)row * ep.ldo1 + col] = (half_t)(v * ep.scale);
        } else if (EPI == 2) {
          o2[(size_t)row * ep.ldo2 + col] = (half_t)v;
        } else {
          v += ep.bias[col];
          int b = row >> 12;
          float g = ep.gate[(size_t)b * QKV_N + col];
          float r = ep.resid[(size_t)row * DIM + col];
          ep.outF[(size_t)row * ep.ldoF + col] = r + g * v;
        }
      }
    }
  }
}

// ---- vectorized 64x64 f32->fp16 transpose tile ----
__device__ __forceinline__ void tp_tile(
    const float* __restrict__ in, half_t* __restrict__ out, int R, int C,
    int r0, int c0, float (*s)[65], int t)
{
  const int tx = t & 15, ty = t >> 4;   // 16 x 16
#pragma unroll
  for (int j = 0; j < 4; ++j) {
    int r = ty + j * 16;
    float4 v = *(const float4*)&in[(size_t)(r0 + r) * C + c0 + tx * 4];
    s[r][tx * 4 + 0] = v.x; s[r][tx * 4 + 1] = v.y;
    s[r][tx * 4 + 2] = v.z; s[r][tx * 4 + 3] = v.w;
  }
  __syncthreads();
#pragma unroll
  for (int j = 0; j < 4; ++j) {
    int c = ty + j * 16;
    half_t o[4] = {(half_t)s[tx * 4 + 0][c], (half_t)s[tx * 4 + 1][c],
                   (half_t)s[tx * 4 + 2][c], (half_t)s[tx * 4 + 3][c]};
    *(uint2*)&out[(size_t)(c0 + c) * R + r0 + tx * 4] = *(uint2*)o;
  }
}

#define NBW1 ((N1 / 64) * (DIM / 64))      // 16128
#define NBW2 ((DIM / 64) * (CAT_N / 64))   // 11520
#define NBEMB ((QKV_N / 256) * BATCH)      // 72

// fused pre-pass: transpose w1, transpose w2, emb = silu(temb)@w_lin+b_lin
__global__ __launch_bounds__(256) void k_pre(
    const float* __restrict__ w1, half_t* __restrict__ w1T,
    const float* __restrict__ w2, half_t* __restrict__ w2T,
    const float* __restrict__ temb, const float* __restrict__ w_lin,
    const float* __restrict__ b_lin, float* __restrict__ emb)
{
  __shared__ float s[64][65];
  int id = blockIdx.x;
  if (id < NBW1) {
    int cx = id % (N1 / 64), ry = id / (N1 / 64);
    tp_tile(w1, w1T, DIM, N1, ry * 64, cx * 64, s, threadIdx.x);
    return;
  }
  id -= NBW1;
  if (id < NBW2) {
    int cx = id % (DIM / 64), ry = id / (DIM / 64);
    tp_tile(w2, w2T, CAT_N, DIM, ry * 64, cx * 64, s, threadIdx.x);
    return;
  }
  id -= NBW2;
  {
    float* sf = &s[0][0];
    int b = id / (QKV_N / 256);
    int col = (id % (QKV_N / 256)) * 256 + threadIdx.x;
    const float* tr = temb + (size_t)b * DIM;
    for (int k = threadIdx.x; k < DIM; k += 256) {
      float x = tr[k];
      sf[k] = x / (1.f + __expf(-x));
    }
    __syncthreads();
    float acc = b_lin[col];
    for (int k = 0; k < DIM; k += 4) {
      acc += sf[k] * w_lin[(size_t)k * QKV_N + col]
           + sf[k + 1] * w_lin[(size_t)(k + 1) * QKV_N + col]
           + sf[k + 2] * w_lin[(size_t)(k + 2) * QKV_N + col]
           + sf[k + 3] * w_lin[(size_t)(k + 3) * QKV_N + col];
    }
    emb[(size_t)b * QKV_N + col] = acc;
  }
}

// LayerNorm + (1+scale)*xhat + shift -> fp16
__global__ __launch_bounds__(256) void k_lnmod(
    const float* __restrict__ hs, const float* __restrict__ emb,
    half_t* __restrict__ xmod)
{
  int row = blockIdx.x;
  int b = row >> 12;
  const float* x = hs + (size_t)row * DIM;
  int t = threadIdx.x;
  float s = 0.f, s2 = 0.f;
  float4 v[3];
#pragma unroll
  for (int i = 0; i < 3; ++i) {
    v[i] = ((const float4*)x)[t + 256 * i];
    s  += v[i].x + v[i].y + v[i].z + v[i].w;
    s2 += v[i].x * v[i].x + v[i].y * v[i].y + v[i].z * v[i].z + v[i].w * v[i].w;
  }
  for (int o = 32; o; o >>= 1) { s += __shfl_xor(s, o); s2 += __shfl_xor(s2, o); }
  __shared__ float rs[4], rs2[4];
  int lane = t & 63, w = t >> 6;
  if (lane == 0) { rs[w] = s; rs2[w] = s2; }
  __syncthreads();
  s = rs[0] + rs[1] + rs[2] + rs[3];
  s2 = rs2[0] + rs2[1] + rs2[2] + rs2[3];
  float mu = s * (1.f / DIM);
  float var = s2 * (1.f / DIM) - mu * mu;
  float rstd = rsqrtf(var + 1e-6f);
  const float* shift = emb + (size_t)b * QKV_N;
  const float* scale = shift + DIM;
#pragma unroll
  for (int i = 0; i < 3; ++i) {
    int g = t + 256 * i;
    float4 sc = ((const float4*)scale)[g];
    float4 sh = ((const float4*)shift)[g];
    half_t ob[4];
    float vv[4] = {v[i].x, v[i].y, v[i].z, v[i].w};
    float scv[4] = {sc.x, sc.y, sc.z, sc.w};
    float shv[4] = {sh.x, sh.y, sh.z, sh.w};
#pragma unroll
    for (int j = 0; j < 4; ++j) {
      float xn = (vv[j] - mu) * rstd;
      ob[j] = (half_t)(xn * (1.f + scv[j]) + shv[j]);
    }
    *(uint2*)&xmod[(size_t)row * DIM + g * 4] = *(uint2*)ob;
  }
}

#define NROPE ((NROWS * NH * 2) / 4)                   // 98304
#define NVT   ((LSEQ / 64) * (DIM / 64) * BATCH)       // 6144

// fused: RMS+RoPE on q,k (in-place) AND v -> vT transpose
__global__ __launch_bounds__(256) void k_ropevt(
    half_t* __restrict__ qkv, const float* __restrict__ rope,
    const float* __restrict__ q_scale, const float* __restrict__ k_scale,
    half_t* __restrict__ vT)
{
  __shared__ half_t s[64][65];
  int id = blockIdx.x;
  if (id < NROPE) {
    int w = id * 4 + (threadIdx.x >> 6);
    int lane = threadIdx.x & 63;
    int qk = w & 1;
    int hr = w >> 1;               // bl*24 + h
    int h = hr % 24;
    int bl = hr / 24;              // b*4096 + l
    size_t base = (size_t)bl * QKV_N + qk * DIM + h * DH;
    float x0 = (float)qkv[base + lane * 2];
    float x1 = (float)qkv[base + lane * 2 + 1];
    float ss = x0 * x0 + x1 * x1;
    for (int o = 32; o; o >>= 1) ss += __shfl_xor(ss, o);
    float r = rsqrtf(ss * (1.f / DH) + 1e-6f);
    const float* sc = qk ? k_scale : q_scale;
    float xs0 = x0 * r * sc[lane * 2];
    float xs1 = x1 * r * sc[lane * 2 + 1];
    int l = bl & (LSEQ - 1);
    float4 fr = ((const float4*)rope)[(size_t)l * 64 + lane];
    qkv[base + lane * 2]     = (half_t)(fr.x * xs0 + fr.y * xs1);
    qkv[base + lane * 2 + 1] = (half_t)(fr.z * xs0 + fr.w * xs1);
    return;
  }
  id -= NROPE;
  {
    int nb = (LSEQ / 64) * (DIM / 64);
    int b = id / nb;
    int rem = id % nb;
    int l0 = (rem % (LSEQ / 64)) * 64, d0 = (rem / (LSEQ / 64)) * 64;
    int tx = threadIdx.x & 63, ty = threadIdx.x >> 6;
#pragma unroll
    for (int j = 0; j < 16; ++j) {
      int l = ty + j * 4;
      s[l][tx] = qkv[(size_t)(b * LSEQ + l0 + l) * QKV_N + 2 * DIM + d0 + tx];
    }
    __syncthreads();
#pragma unroll
    for (int j = 0; j < 16; ++j) {
      int d = ty + j * 4;
      vT[((size_t)b * DIM + d0 + d) * LSEQ + l0 + tx] = s[tx][d];
    }
  }
}

// row softmax: S (4096 fp16) -> P fp16; grid = BATCH*LSEQ
__global__ __launch_bounds__(256) void k_softmax(
    const half_t* __restrict__ S, half_t* __restrict__ P)
{
  int row = blockIdx.x;
  const half_t* srow = S + (size_t)row * LSEQ;
  int t = threadIdx.x;
  f16x8 hv[2];
  float vf[16];
  float mx = -1e30f;
#pragma unroll
  for (int i = 0; i < 2; ++i) {
    hv[i] = ((const f16x8*)srow)[t + 256 * i];
#pragma unroll
    for (int j = 0; j < 8; ++j) {
      vf[i * 8 + j] = (float)hv[i][j];
      mx = fmaxf(mx, vf[i * 8 + j]);
    }
  }
  for (int o = 32; o; o >>= 1) mx = fmaxf(mx, __shfl_xor(mx, o));
  __shared__ float rmx[4], rsum[4];
  int lane = t & 63, w = t >> 6;
  if (lane == 0) rmx[w] = mx;
  __syncthreads();
  mx = fmaxf(fmaxf(rmx[0], rmx[1]), fmaxf(rmx[2], rmx[3]));
  float s = 0.f;
#pragma unroll
  for (int i = 0; i < 16; ++i) {
    vf[i] = __expf(vf[i] - mx);
    s += vf[i];
  }
  for (int o = 32; o; o >>= 1) s += __shfl_xor(s, o);
  if (lane == 0) rsum[w] = s;
  __syncthreads();
  s = rsum[0] + rsum[1] + rsum[2] + rsum[3];
  float inv = 1.f / s;
#pragma unroll
  for (int i = 0; i < 2; ++i) {
    f16x8 ob;
#pragma unroll
    for (int j = 0; j < 8; ++j) ob[j] = (half_t)(vf[i * 8 + j] * inv);
    ((f16x8*)&P[(size_t)row * LSEQ])[t + 256 * i] = ob;
  }
}

// final: out = resid + gate * (p0 + p1 + b2)   (p0,p1 fp16 split-K partials)
__global__ __launch_bounds__(256) void k_final(
    const half_t* __restrict__ part, const float* __restrict__ hs,
    const float* __restrict__ emb, const float* __restrict__ b2,
    float* __restrict__ out)
{
  int row = blockIdx.x;
  int b = row >> 12;
  int t = threadIdx.x;
  const float* gate = emb + (size_t)b * QKV_N + 2 * DIM;
  const half_t* p0 = part + (size_t)row * DIM;
  const half_t* p1 = part + (size_t)NROWS * DIM + (size_t)row * DIM;
  const float* rr = hs + (size_t)row * DIM;
  float* orow = out + (size_t)row * DIM;
#pragma unroll
  for (int i = 0; i < 3; ++i) {
    int g = t + 256 * i;                         // float4 group index
    short4 a = ((const short4*)p0)[g];
    short4 c = ((const short4*)p1)[g];
    float4 r4 = ((const float4*)rr)[g];
    float4 g4 = ((const float4*)gate)[g];
    float4 b4 = ((const float4*)b2)[g];
    float4 o;
    o.x = r4.x + g4.x * ((float)*(half_t*)&a.x + (float)*(half_t*)&c.x + b4.x);
    o.y = r4.y + g4.y * ((float)*(half_t*)&a.y + (float)*(half_t*)&c.y + b4.y);
    o.z = r4.z + g4.z * ((float)*(half_t*)&a.z + (float)*(half_t*)&c.z + b4.z);
    o.w = r4.w + g4.w * ((float)*(half_t*)&a.w + (float)*(half_t*)&c.w + b4.w);
    ((float4*)orow)[g] = o;
  }
}

extern "C" void kernel_launch(void* const* d_in, const int* in_sizes, int n_in,
                              void* d_out, int out_size, void* d_ws, size_t ws_size,
                              hipStream_t stream) {
  const float* hs      = (const float*)d_in[0];
  const float* temb    = (const float*)d_in[1];
  const float* rope    = (const float*)d_in[2];
  const float* w_lin   = (const float*)d_in[3];
  const float* b_lin   = (const float*)d_in[4];
  const float* w1      = (const float*)d_in[5];
  const float* b1      = (const float*)d_in[6];
  const float* w2      = (const float*)d_in[7];
  const float* b2      = (const float*)d_in[8];
  const float* q_scale = (const float*)d_in[9];
  const float* k_scale = (const float*)d_in[10];
  float* out = (float*)d_out;

  char* ws = (char*)d_ws;
  size_t off = 0;
  auto alloc = [&](size_t bytes) { char* p = ws + off; off += (bytes + 255) & ~(size_t)255; return p; };
  float*  emb    = (float*) alloc((size_t)BATCH * QKV_N * 4);
  half_t* xmod   = (half_t*)alloc((size_t)NROWS * DIM * 2);
  half_t* w1T    = (half_t*)alloc((size_t)N1 * DIM * 2);
  half_t* w2T    = (half_t*)alloc((size_t)DIM * CAT_N * 2);
  half_t* qkv    = (half_t*)alloc((size_t)NROWS * QKV_N * 2);
  half_t* concat = (half_t*)alloc((size_t)NROWS * CAT_N * 2);
  half_t* vT     = (half_t*)alloc((size_t)BATCH * DIM * LSEQ * 2);
  half_t* Sbuf   = (half_t*)alloc((size_t)BATCH * LSEQ * LSEQ * 2);
  half_t* Pbuf   = (half_t*)alloc((size_t)BATCH * LSEQ * LSEQ * 2);
  // split-K partials (2 x NROWS x DIM fp16 = 100MB) alias the dead
  // xmod+w1T region (182MB contiguous; both consumed by gemm<0> only).
  half_t* part   = xmod;
  (void)ws_size; (void)n_in; (void)in_sizes; (void)out_size;

  // fused pre-pass: both weight transposes + emb
  k_pre<<<NBW1 + NBW2 + NBEMB, 256, 0, stream>>>(w1, w1T, w2, w2T, temb, w_lin, b_lin, emb);
  k_lnmod<<<NROWS, 256, 0, stream>>>(hs, emb, xmod);

  // GEMM1: proj = xmod @ w1 + b1 ; qkv part -> qkv buf, mlp part -> gelu -> concat[:,3072:]
  EpiParams ep1 = {b1, nullptr, 0, qkv, QKV_N, concat, CAT_N, nullptr, nullptr, 0.f};
  gemm256<0><<<(N1 / 256) * (NROWS / 256), 512, 0, stream>>>(
      xmod, DIM, w1T, DIM, N1 / 256, (N1 / 256) * (NROWS / 256), 0, 0, 0, QKV_N, DIM, ep1);

  // fused RMS+RoPE (q,k) + vT transpose
  k_ropevt<<<NROPE + NVT, 256, 0, stream>>>(qkv, rope, q_scale, k_scale, vT);

  // batched attention: S = q @ k^T (both batches, one launch)
  EpiParams epS = {nullptr, nullptr, 0, Sbuf, LSEQ, nullptr, 0, nullptr, nullptr, 0.08838834764831845f};
  gemm256<1><<<(LSEQ / 256) * (LSEQ / 256) * BATCH, 512, 0, stream>>>(
      qkv, QKV_N, qkv + DIM, QKV_N,
      LSEQ / 256, (LSEQ / 256) * (LSEQ / 256),
      (size_t)LSEQ * QKV_N, (size_t)LSEQ * QKV_N, (size_t)LSEQ * LSEQ,
      0, DIM, epS);
  k_softmax<<<BATCH * LSEQ, 256, 0, stream>>>(Sbuf, Pbuf);
  // batched PV: attn_out = P @ vT^T -> concat[:, :DIM]
  EpiParams epPV = {nullptr, nullptr, 0, nullptr, 0, concat, CAT_N, nullptr, nullptr, 0.f};
  gemm256<2><<<(DIM / 256) * (LSEQ / 256) * BATCH, 512, 0, stream>>>(
      Pbuf, LSEQ, vT, LSEQ,
      DIM / 256, (DIM / 256) * (LSEQ / 256),
      (size_t)LSEQ * LSEQ, (size_t)DIM * LSEQ, (size_t)LSEQ * CAT_N,
      0, LSEQ, epPV);

  // GEMM2 split-K=2: partials (fp16) = concat[:, sl*7680:+7680] @ w2T-slice
  EpiParams ep2 = {nullptr, nullptr, 0, nullptr, 0, part, DIM, nullptr, nullptr, 0.f};
  gemm256<2><<<(DIM / 256) * (NROWS / 256) * 2, 512, 0, stream>>>(
      concat, CAT_N, w2T, CAT_N,
      DIM / 256, (DIM / 256) * (NROWS / 256),
      (size_t)(CAT_N / 2), (size_t)(CAT_N / 2), (size_t)NROWS * DIM,
      0, CAT_N / 2, ep2);
  // final: out = resid + gate * (p0 + p1 + b2)
  k_final<<<NROWS, 256, 0, stream>>>(part, hs, emb, b2, out);
}